// Round 1
// 125.774 us; speedup vs baseline: 1.0817x; 1.0817x over previous
//
#include <hip/hip_runtime.h>
#include <hip/hip_bf16.h>

typedef __hip_bfloat16 bf16;
typedef __bf16 bfx8 __attribute__((ext_vector_type(8)));
typedef float f32x4 __attribute__((ext_vector_type(4)));

#define Bk   8
#define Ck   384
#define NHk  8
#define Dk   48
#define Dp   64
#define Nk   1024
#define O3   1152

// ---------------------------------------------------------------------------
// ALL MFMA operands live in fragment-order swizzle [R/16][C/8][16][8]: a
// wave's fragment load = base + lane*16B = one contiguous 1KB burst (R8).
//
// Workspace (bf16 elems):
//   Xs: [b][n/16][48][16][8]        3,145,728   (x^T swizzled)
//   Wq: [o/16][48][16][8]             442,368
//   Wp: [o/16][48][16][8]             147,456
//   Qs: [b][hd][n/16][8][16][8]     4,194,304   (scale*log2e folded; chunks 6,7 zero)
//   Ks: [b][hd][n/16][8][16][8]     4,194,304   (chunks 6,7 zero)
//   Vs: [b][hd][d/16][n/8][16][8]   3,145,728   (V^T swizzled)
//   AO: [b][n/16][48][16][8]        3,145,728   (swizzled for proj)
//
// R10: attention restructured for K/V reuse + XCD locality.
//   - 32 q per wave (2 q-tiles share every K/V fragment load): K/V global
//     read traffic 918 MB -> 459 MB.
//   - grid (hd, b, bx): linear id % 8 == hd, so all 8 blocks of one head
//     land on ONE XCD; per-XCD K/V reuse set = 1.75 MB < 4 MB L2 (was 21 MB
//     scattered -> L3-bound).
//   - K regs double-buffered (prefetch next 64-key chunk during current
//     body); V loads issued before exp2/pack so L2 latency hides under VALU.
//   - no asm waitcnt fences: per-wave LDS ordering is a compiler obligation;
//     the old "memory" clobbers blocked global-load hoisting.
// ---------------------------------------------------------------------------

// Prep 1: transpose+convert x [b][c][n] fp32 -> Xs swizzled bf16.
__global__ __launch_bounds__(256) void xpose_kernel(
    const float* __restrict__ x, bf16* __restrict__ Xs)
{
    __shared__ bf16 tile[32][33];
    const int b = blockIdx.z, c0 = blockIdx.y * 32, n0 = blockIdx.x * 32;
    const int tn = threadIdx.x & 31, tc = threadIdx.x >> 5;
    const float* xb = x + (size_t)b * Ck * Nk;
    #pragma unroll
    for (int i = 0; i < 4; ++i)
        tile[tc + 8 * i][tn] = __float2bfloat16(xb[(size_t)(c0 + tc + 8 * i) * Nk + n0 + tn]);
    __syncthreads();
    bf16* base = Xs + ((size_t)b * 64 + (n0 >> 4)) * 48 * 128 + (c0 >> 3) * 128;
    #pragma unroll
    for (int i = 0; i < 4; ++i) {
        int n_loc = tc + 8 * i, c_loc = tn;
        base[(size_t)(n_loc >> 4) * 6144 + (c_loc >> 3) * 128 +
             (n_loc & 15) * 8 + (c_loc & 7)] = tile[c_loc][n_loc];
    }
}

// Prep 2: convert+swizzle weights; ALSO zero Q/K pad chunks (cd=6,7).
__global__ __launch_bounds__(256) void wconv_kernel(
    const float* __restrict__ wq, const float* __restrict__ wp,
    bf16* __restrict__ Wq, bf16* __restrict__ Wp,
    bf16* __restrict__ Qs, bf16* __restrict__ Ks)
{
    int i = blockIdx.x * 256 + threadIdx.x;
    if (i < O3 * Ck) {
        int o = i / Ck, c = i - o * Ck;
        Wq[((size_t)(o >> 4) * 48 + (c >> 3)) * 128 + (o & 15) * 8 + (c & 7)] =
            __float2bfloat16(wq[i]);
    }
    if (i < Ck * Ck) {
        int o = i / Ck, c = i - o * Ck;
        Wp[((size_t)(o >> 4) * 48 + (c >> 3)) * 128 + (o & 15) * 8 + (c & 7)] =
            __float2bfloat16(wp[i]);
    }
    if (i < 262144) {           // 2 bufs x 64 heads x 64 grp x 2 chunks x 16 int4
        int buf = i >> 17;
        int r17 = i & 131071;
        int head = r17 >> 11;
        int r11 = r17 & 2047;
        int g = r11 >> 5, c5 = r11 & 31;
        int cd = 6 + (c5 >> 4), e = c5 & 15;
        bf16* p = (buf ? Ks : Qs) + (size_t)head * 65536 +
                  ((size_t)g * 8 + cd) * 128 + e * 8;
        *(int4*)p = (int4){0, 0, 0, 0};
    }
}

// ---------------------------------------------------------------------------
// Kernel 1: QKV GEMM, pure-MFMA, no LDS (unchanged from R9).
// ---------------------------------------------------------------------------
__global__ __launch_bounds__(256) void qkv_mfma_kernel(
    const bf16* __restrict__ Xs, const bf16* __restrict__ Wq,
    const float* __restrict__ bias,
    bf16* __restrict__ Qs, bf16* __restrict__ Ks, bf16* __restrict__ Vs)
{
    const int b    = blockIdx.z;
    const int by   = blockIdx.y;
    const int bx   = blockIdx.x;
    const int o0   = by * 64;
    const int n0   = bx * 128;
    const int wave = threadIdx.x >> 6;
    const int lane = threadIdx.x & 63;
    const int l15  = lane & 15, quad = lane >> 4;
    const int t3   = o0 / Ck;

    const bf16* xg[2];
    const bf16* wg[4];
    #pragma unroll
    for (int i = 0; i < 2; ++i)
        xg[i] = Xs + ((size_t)(b * 64 + bx * 8 + wave * 2 + i) * 48) * 128 + lane * 8;
    #pragma unroll
    for (int j = 0; j < 4; ++j)
        wg[j] = Wq + ((size_t)(by * 4 + j) * 48) * 128 + lane * 8;

    f32x4 acc[8];
    #pragma unroll
    for (int i = 0; i < 8; ++i) acc[i] = (f32x4){0.f, 0.f, 0.f, 0.f};

    if (t3 < 2) {
        #pragma unroll
        for (int s = 0; s < 12; ++s) {
            bfx8 fx[2], fw[4];
            #pragma unroll
            for (int i = 0; i < 2; ++i) fx[i] = *(const bfx8*)(xg[i] + s * 512);
            #pragma unroll
            for (int j = 0; j < 4; ++j) fw[j] = *(const bfx8*)(wg[j] + s * 512);
            #pragma unroll
            for (int i = 0; i < 2; ++i)
                #pragma unroll
                for (int j = 0; j < 4; ++j)
                    acc[i * 4 + j] = __builtin_amdgcn_mfma_f32_16x16x32_bf16(
                        fx[i], fw[j], acc[i * 4 + j], 0, 0, 0);
        }
        // 48^-0.5 * log2(e) folded into Q (softmax uses exp2)
        const float qscale = 0.2082350964f;
        #pragma unroll
        for (int j = 0; j < 4; ++j) {
            int o  = o0 + j * 16 + l15;
            float bi = bias[o];
            int r  = o - t3 * Ck;
            int hd = r / Dk, d = r - hd * Dk;
            bf16* hb = (t3 == 0 ? Qs : Ks) + (size_t)(b * NHk + hd) * 65536
                     + (d >> 3) * 128 + (d & 7);
            #pragma unroll
            for (int i = 0; i < 2; ++i) {
                #pragma unroll
                for (int reg = 0; reg < 4; ++reg) {
                    int npos = n0 + wave * 32 + i * 16 + quad * 4 + reg;
                    float v = acc[i * 4 + j][reg] + bi;
                    if (t3 == 0) v *= qscale;
                    hb[(size_t)(npos >> 4) * 1024 + (npos & 15) * 8] = __float2bfloat16(v);
                }
            }
        }
    } else {
        #pragma unroll
        for (int s = 0; s < 12; ++s) {
            bfx8 fx[2], fw[4];
            #pragma unroll
            for (int i = 0; i < 2; ++i) fx[i] = *(const bfx8*)(xg[i] + s * 512);
            #pragma unroll
            for (int j = 0; j < 4; ++j) fw[j] = *(const bfx8*)(wg[j] + s * 512);
            #pragma unroll
            for (int j = 0; j < 4; ++j)
                #pragma unroll
                for (int i = 0; i < 2; ++i)
                    acc[j * 2 + i] = __builtin_amdgcn_mfma_f32_16x16x32_bf16(
                        fw[j], fx[i], acc[j * 2 + i], 0, 0, 0);
        }
        #pragma unroll
        for (int j = 0; j < 4; ++j) {
            #pragma unroll
            for (int reg = 0; reg < 4; ++reg) {
                int o  = o0 + j * 16 + quad * 4 + reg;
                float bi = bias[o];
                int r  = o - 2 * Ck;
                int hd = r / Dk, d = r - hd * Dk;
                bf16* vb = Vs + (size_t)(b * NHk + hd) * 49152
                         + ((size_t)(d >> 4) * 128) * 128 + (d & 15) * 8;
                #pragma unroll
                for (int i = 0; i < 2; ++i) {
                    int npos = n0 + wave * 32 + i * 16 + l15;
                    vb[(size_t)(npos >> 3) * 128 + (npos & 7)] =
                        __float2bfloat16(acc[j * 2 + i][reg] + bi);
                }
            }
        }
    }
}

// ---------------------------------------------------------------------------
// Kernel 2 (R10): MFMA attention — 128 q per block, 32 q per wave (2 q-tiles
// sharing each K/V fragment load). Grid (hd, b, bx=8) = 512 blocks = 2/CU =
// 8 waves/CU; id%8==hd pins each head's 8 blocks to ONE XCD so K/V re-reads
// are L2 hits (reuse set 1.75 MB/XCD). K regs double-buffered across chunks;
// V issued before the exp2/pack section. No barriers; per-wave LDS only for
// the P round-trip.
// ---------------------------------------------------------------------------
__global__ __launch_bounds__(256, 2) void attn_kernel(
    const bf16* __restrict__ Qs, const bf16* __restrict__ Ks,
    const bf16* __restrict__ Vs, bf16* __restrict__ AO)
{
    __shared__ __align__(16) short Ps[4 * 2 * 16 * 72];
    __shared__ float sums[4][2][16];

    const int hd   = blockIdx.x;
    const int b    = blockIdx.y;
    const int bx   = blockIdx.z;       // 8 q-slabs of 128
    const int t    = threadIdx.x;
    const int wave = t >> 6;
    const int lane = t & 63;
    const int l15  = lane & 15;
    const int quad = lane >> 4;
    const int grp16 = (bx * 4 + wave) * 2;   // first 16-q group of this wave

    const bf16* qb = Qs + (size_t)(b * NHk + hd) * 65536;
    const bf16* kb = Ks + (size_t)(b * NHk + hd) * 65536;
    const bf16* vb = Vs + (size_t)(b * NHk + hd) * 49152;

    // Q fragments (burst loads): B[k=d][n=q=l15] for 2 q-tiles
    bfx8 bq[2][2];
    #pragma unroll
    for (int qt = 0; qt < 2; ++qt) {
        const bf16* qp = qb + ((size_t)(grp16 + qt) * 8 + quad) * 128 + l15 * 8;
        bq[qt][0] = *(const bfx8*)(qp);
        bq[qt][1] = *(const bfx8*)(qp + 512);
    }

    float l_run[2] = {0.f, 0.f};
    f32x4 oacc[2][3];
    #pragma unroll
    for (int qt = 0; qt < 2; ++qt)
        #pragma unroll
        for (int dc = 0; dc < 3; ++dc) oacc[qt][dc] = (f32x4){0.f, 0.f, 0.f, 0.f};

    short* const PsW[2] = { Ps + wave * 2304, Ps + wave * 2304 + 1152 };

    auto loadK = [&](bfx8* kf, int k0) {
        const bf16* kp0 = kb + (size_t)k0 * 64 + quad * 128 + l15 * 8;
        #pragma unroll
        for (int s = 0; s < 4; ++s) {
            kf[2 * s]     = *(const bfx8*)(kp0 + s * 1024);
            kf[2 * s + 1] = *(const bfx8*)(kp0 + s * 1024 + 512);
        }
    };
    auto loadV = [&](bfx8* vf, int k0) {
        const bf16* vp0 = vb + ((size_t)(k0 >> 3) + quad) * 128 + l15 * 8;
        #pragma unroll
        for (int dc = 0; dc < 3; ++dc) {
            vf[2 * dc]     = *(const bfx8*)(vp0 + (size_t)dc * 16384);
            vf[2 * dc + 1] = *(const bfx8*)(vp0 + (size_t)dc * 16384 + 512);
        }
    };

    auto step = [&](const bfx8* kf, bfx8* kfn, int k0, bool pf) {
        // V for this chunk: issue first so its latency hides under exp2/pack
        bfx8 vf[6];
        loadV(vf, k0);
        // prefetch next chunk's K (consumed by the NEXT step)
        if (pf) loadK(kfn, k0 + 64);

        // S^T = K Q^T: D[key][q], K fragments shared by both q-tiles
        f32x4 sf[2][4];
        #pragma unroll
        for (int s = 0; s < 4; ++s) {
            #pragma unroll
            for (int qt = 0; qt < 2; ++qt) {
                f32x4 z = (f32x4){0.f, 0.f, 0.f, 0.f};
                z = __builtin_amdgcn_mfma_f32_16x16x32_bf16(kf[2 * s],     bq[qt][0], z, 0, 0, 0);
                z = __builtin_amdgcn_mfma_f32_16x16x32_bf16(kf[2 * s + 1], bq[qt][1], z, 0, 0, 0);
                sf[qt][s] = z;
            }
        }

        // exp2 (no max subtraction), pack 4 keys -> b64 write, accumulate l
        #pragma unroll
        for (int qt = 0; qt < 2; ++qt) {
            float lsum = 0.f;
            #pragma unroll
            for (int s = 0; s < 4; ++s) {
                ushort4 pk;
                float e0 = __builtin_amdgcn_exp2f(sf[qt][s][0]);
                float e1 = __builtin_amdgcn_exp2f(sf[qt][s][1]);
                float e2 = __builtin_amdgcn_exp2f(sf[qt][s][2]);
                float e3 = __builtin_amdgcn_exp2f(sf[qt][s][3]);
                lsum += (e0 + e1) + (e2 + e3);
                bf16 h0 = __float2bfloat16(e0), h1 = __float2bfloat16(e1);
                bf16 h2 = __float2bfloat16(e2), h3 = __float2bfloat16(e3);
                pk.x = *(unsigned short*)&h0; pk.y = *(unsigned short*)&h1;
                pk.z = *(unsigned short*)&h2; pk.w = *(unsigned short*)&h3;
                *(ushort4*)&PsW[qt][l15 * 72 + s * 16 + quad * 4] = pk;
            }
            l_run[qt] += lsum;
        }

        // O += P V: A-frags from per-wave LDS (compiler inserts lgkmcnt),
        // V fragments shared by both q-tiles
        #pragma unroll
        for (int qt = 0; qt < 2; ++qt) {
            const bfx8 ap0 = *(const bfx8*)&PsW[qt][l15 * 72 + quad * 8];
            const bfx8 ap1 = *(const bfx8*)&PsW[qt][l15 * 72 + 32 + quad * 8];
            #pragma unroll
            for (int dc = 0; dc < 3; ++dc) {
                oacc[qt][dc] = __builtin_amdgcn_mfma_f32_16x16x32_bf16(
                    ap0, vf[2 * dc], oacc[qt][dc], 0, 0, 0);
                oacc[qt][dc] = __builtin_amdgcn_mfma_f32_16x16x32_bf16(
                    ap1, vf[2 * dc + 1], oacc[qt][dc], 0, 0, 0);
            }
        }
    };

    bfx8 kfA[8], kfB[8];
    loadK(kfA, 0);
    #pragma unroll 1
    for (int k0 = 0; k0 < Nk; k0 += 128) {
        step(kfA, kfB, k0, true);
        step(kfB, kfA, k0 + 64, k0 + 128 < Nk);
    }

    // cross-lane reduce l over quads (per q-tile)
    #pragma unroll
    for (int qt = 0; qt < 2; ++qt) {
        float lt = l_run[qt];
        lt += __shfl_xor(lt, 16, 64);
        lt += __shfl_xor(lt, 32, 64);
        sums[wave][qt][l15] = lt;
    }

    // normalize into per-wave LDS (stride 64 shorts, 16B-aligned rows)
    #pragma unroll
    for (int qt = 0; qt < 2; ++qt) {
        short* OsW = PsW[qt];   // 16*64 = 1024 shorts < 1152 region
        #pragma unroll
        for (int r = 0; r < 4; ++r) {
            int qi = quad * 4 + r;
            float rli = 1.0f / sums[wave][qt][qi];
            #pragma unroll
            for (int dcc = 0; dcc < 3; ++dcc) {
                bf16 hb = __float2bfloat16(oacc[qt][dcc][r] * rli);
                OsW[qi * 64 + dcc * 16 + l15] = *(short*)&hb;
            }
        }
    }

    // swizzled AO store: groups grp16+qt, chunks hd*6 + (0..5); 96 int4 each
    #pragma unroll
    for (int qt = 0; qt < 2; ++qt) {
        bf16* aob = AO + (((size_t)b * 64 + grp16 + qt) * 48 + hd * 6) * 128;
        short* OsW = PsW[qt];
        int u = lane;
        int4 v = *(const int4*)&OsW[(u & 15) * 64 + (u >> 4) * 8];
        *(int4*)(aob + u * 8) = v;
        if (lane < 32) {
            int u2 = 64 + lane;
            int4 v2 = *(const int4*)&OsW[(u2 & 15) * 64 + (u2 >> 4) * 8];
            *(int4*)(aob + u2 * 8) = v2;
        }
    }
}

// ---------------------------------------------------------------------------
// Kernel 3: projection GEMM, pure-MFMA, swizzled operands (unchanged R8).
// ---------------------------------------------------------------------------
__global__ __launch_bounds__(256) void proj_mfma_kernel(
    const bf16* __restrict__ AO, const bf16* __restrict__ Wp,
    const float* __restrict__ bias, float* __restrict__ out)
{
    const int b    = blockIdx.z;
    const int by   = blockIdx.y;
    const int bx   = blockIdx.x;
    const int o0   = by * 64;
    const int n0   = bx * 128;
    const int wave = threadIdx.x >> 6;
    const int lane = threadIdx.x & 63;
    const int l15  = lane & 15, quad = lane >> 4;

    const bf16* ag[2];
    const bf16* wg[4];
    #pragma unroll
    for (int i = 0; i < 2; ++i)
        ag[i] = AO + ((size_t)(b * 64 + bx * 8 + wave * 2 + i) * 48) * 128 + lane * 8;
    #pragma unroll
    for (int j = 0; j < 4; ++j)
        wg[j] = Wp + ((size_t)(by * 4 + j) * 48) * 128 + lane * 8;

    f32x4 acc[8];
    #pragma unroll
    for (int i = 0; i < 8; ++i) acc[i] = (f32x4){0.f, 0.f, 0.f, 0.f};

    #pragma unroll
    for (int s = 0; s < 12; ++s) {
        bfx8 fx[2], fw[4];
        #pragma unroll
        for (int i = 0; i < 2; ++i) fx[i] = *(const bfx8*)(ag[i] + s * 512);
        #pragma unroll
        for (int j = 0; j < 4; ++j) fw[j] = *(const bfx8*)(wg[j] + s * 512);
        #pragma unroll
        for (int j = 0; j < 4; ++j)
            #pragma unroll
            for (int i = 0; i < 2; ++i)
                acc[j * 2 + i] = __builtin_amdgcn_mfma_f32_16x16x32_bf16(
                    fw[j], fx[i], acc[j * 2 + i], 0, 0, 0);
    }

    #pragma unroll
    for (int j = 0; j < 4; ++j) {
        #pragma unroll
        for (int reg = 0; reg < 4; ++reg) {
            int o  = o0 + j * 16 + quad * 4 + reg;
            float bi = bias[o];
            #pragma unroll
            for (int i = 0; i < 2; ++i) {
                int npos = n0 + wave * 32 + i * 16 + l15;
                out[((size_t)b * Ck + o) * Nk + npos] = acc[j * 2 + i][reg] + bi;
            }
        }
    }
}

extern "C" void kernel_launch(void* const* d_in, const int* in_sizes, int n_in,
                              void* d_out, int out_size, void* d_ws, size_t ws_size,
                              hipStream_t stream)
{
    const float* x      = (const float*)d_in[0];
    const float* w_qkv  = (const float*)d_in[1];
    const float* b_qkv  = (const float*)d_in[2];
    const float* w_proj = (const float*)d_in[3];
    const float* b_proj = (const float*)d_in[4];
    float* out = (float*)d_out;

    const size_t XT_SEG = (size_t)Bk * Nk * Ck;
    const size_t WQ_SEG = (size_t)O3 * Ck;
    const size_t WP_SEG = (size_t)Ck * Ck;
    const size_t QK_SEG = (size_t)Bk * NHk * Nk * Dp;
    const size_t V_SEG  = (size_t)Bk * NHk * Dk * Nk;

    bf16* Xs = (bf16*)d_ws;
    bf16* Wq = Xs + XT_SEG;
    bf16* Wp = Wq + WQ_SEG;
    bf16* Qs = Wp + WP_SEG;
    bf16* Ks = Qs + QK_SEG;
    bf16* Vs = Ks + QK_SEG;
    bf16* AO = Vs + V_SEG;

    xpose_kernel<<<dim3(Nk / 32, Ck / 32, Bk), 256, 0, stream>>>(x, Xs);
    wconv_kernel<<<(O3 * Ck + 255) / 256, 256, 0, stream>>>(
        w_qkv, w_proj, Wq, Wp, Qs, Ks);
    qkv_mfma_kernel<<<dim3(Nk / 128, O3 / 64, Bk), 256, 0, stream>>>(
        Xs, Wq, b_qkv, Qs, Ks, Vs);
    attn_kernel<<<dim3(NHk, Bk, 8), 256, 0, stream>>>(Qs, Ks, Vs, AO);
    proj_mfma_kernel<<<dim3(Nk / 128, Ck / 64, Bk), 256, 0, stream>>>(
        AO, Wp, b_proj, out);
}

// Round 2
// 120.462 us; speedup vs baseline: 1.1294x; 1.0441x over previous
//
#include <hip/hip_runtime.h>
#include <hip/hip_bf16.h>

typedef __hip_bfloat16 bf16;
typedef __bf16 bfx8 __attribute__((ext_vector_type(8)));
typedef float f32x4 __attribute__((ext_vector_type(4)));

#define Bk   8
#define Ck   384
#define NHk  8
#define Dk   48
#define Dp   64
#define Nk   1024
#define O3   1152

// ---------------------------------------------------------------------------
// ALL MFMA operands live in fragment-order swizzle [R/16][C/8][16][8]: a
// wave's fragment load = base + lane*16B = one contiguous 1KB burst (R8).
//
// Workspace (bf16 elems):
//   Xs: [b][n/16][48][16][8]        3,145,728   (x^T swizzled)
//   Wq: [o/16][48][16][8]             442,368
//   Wp: [o/16][48][16][8]             147,456
//   Qs: [b][hd][n/16][8][16][8]     4,194,304   (scale*log2e folded; chunks 6,7 zero)
//   Ks: [b][hd][n/16][8][16][8]     4,194,304   (chunks 6,7 zero)
//   Vs: [b][hd][d/16][n/8][16][8]   3,145,728   (V^T swizzled)
//   AO: [b][n/16][48][16][8]        3,145,728   (swizzled for proj)
//
// R11: kill redundant L2 traffic with LDS staging (fragment layout is
// wave-linear, so global_load_lds width=16 applies directly, linear on both
// sides):
//   - attn: K+V 64-key chunk (8+6 KB) double-buffered in LDS, staged once
//     per block instead of once per wave (459 -> ~124 MB L2 reads); K reg
//     double-buffer dropped. One barrier per chunk; stage for chunk t+1
//     issued before compute of chunk t.
//   - qkv/proj: 48 KB W-tile staged once per block (W was 4x-redundant);
//     W fragments become linear conflict-free ds_reads.
//   - xpose+wconv merged into one launch.
// ---------------------------------------------------------------------------

__device__ __forceinline__ void gload_lds16(const bf16* src, void* dst)
{
    __builtin_amdgcn_global_load_lds(
        (const __attribute__((address_space(1))) void*)src,
        (__attribute__((address_space(3))) void*)dst, 16, 0, 0);
}

// Prep (merged): blocks [0,3072) transpose+convert x; rest convert weights
// and zero Q/K pad chunks.
__global__ __launch_bounds__(256) void prep_kernel(
    const float* __restrict__ x, bf16* __restrict__ Xs,
    const float* __restrict__ wq, const float* __restrict__ wp,
    bf16* __restrict__ Wq, bf16* __restrict__ Wp,
    bf16* __restrict__ Qs, bf16* __restrict__ Ks)
{
    __shared__ bf16 tile[32][33];
    if (blockIdx.x < 3072) {
        const int id = blockIdx.x;
        const int b = id / 384, rem = id % 384;
        const int c0 = ((rem >> 5) % 12) * 32, n0 = (rem & 31) * 32;
        const int tn = threadIdx.x & 31, tc = threadIdx.x >> 5;
        const float* xb = x + (size_t)b * Ck * Nk;
        #pragma unroll
        for (int i = 0; i < 4; ++i)
            tile[tc + 8 * i][tn] = __float2bfloat16(xb[(size_t)(c0 + tc + 8 * i) * Nk + n0 + tn]);
        __syncthreads();
        bf16* base = Xs + ((size_t)b * 64 + (n0 >> 4)) * 48 * 128 + (c0 >> 3) * 128;
        #pragma unroll
        for (int i = 0; i < 4; ++i) {
            int n_loc = tc + 8 * i, c_loc = tn;
            base[(size_t)(n_loc >> 4) * 6144 + (c_loc >> 3) * 128 +
                 (n_loc & 15) * 8 + (c_loc & 7)] = tile[c_loc][n_loc];
        }
    } else {
        int i = (blockIdx.x - 3072) * 256 + threadIdx.x;
        if (i < O3 * Ck) {
            int o = i / Ck, c = i - o * Ck;
            Wq[((size_t)(o >> 4) * 48 + (c >> 3)) * 128 + (o & 15) * 8 + (c & 7)] =
                __float2bfloat16(wq[i]);
        }
        if (i < Ck * Ck) {
            int o = i / Ck, c = i - o * Ck;
            Wp[((size_t)(o >> 4) * 48 + (c >> 3)) * 128 + (o & 15) * 8 + (c & 7)] =
                __float2bfloat16(wp[i]);
        }
        if (i < 262144) {       // 2 bufs x 64 heads x 64 grp x 2 chunks x 16 int4
            int buf = i >> 17;
            int r17 = i & 131071;
            int head = r17 >> 11;
            int r11 = r17 & 2047;
            int g = r11 >> 5, c5 = r11 & 31;
            int cd = 6 + (c5 >> 4), e = c5 & 15;
            bf16* p = (buf ? Ks : Qs) + (size_t)head * 65536 +
                      ((size_t)g * 8 + cd) * 128 + e * 8;
            *(int4*)p = (int4){0, 0, 0, 0};
        }
    }
}

// ---------------------------------------------------------------------------
// Kernel 1: QKV GEMM. W-tile (64o x 384c = 48 KB) staged once per block in
// LDS (was re-read by all 4 waves from L2); X fragments stay direct-L2
// (unique per wave).
// ---------------------------------------------------------------------------
__global__ __launch_bounds__(256) void qkv_mfma_kernel(
    const bf16* __restrict__ Xs, const bf16* __restrict__ Wq,
    const float* __restrict__ bias,
    bf16* __restrict__ Qs, bf16* __restrict__ Ks, bf16* __restrict__ Vs)
{
    __shared__ __align__(16) bf16 Wl[24576];    // 48 KB

    const int b    = blockIdx.z;
    const int by   = blockIdx.y;
    const int bx   = blockIdx.x;
    const int o0   = by * 64;
    const int n0   = bx * 128;
    const int wave = threadIdx.x >> 6;
    const int lane = threadIdx.x & 63;
    const int l15  = lane & 15, quad = lane >> 4;
    const int t3   = o0 / Ck;

    // stage W tile: 48 x 1KB fragment bursts, 12 per wave
    {
        const bf16* wsrc = Wq + (size_t)by * 24576;
        #pragma unroll
        for (int i = 0; i < 12; ++i) {
            int f = wave * 12 + i;
            gload_lds16(wsrc + f * 512 + lane * 8, (char*)Wl + f * 1024);
        }
    }

    const bf16* xg[2];
    #pragma unroll
    for (int i = 0; i < 2; ++i)
        xg[i] = Xs + ((size_t)(b * 64 + bx * 8 + wave * 2 + i) * 48) * 128 + lane * 8;
    const bf16* wl = Wl + lane * 8;

    f32x4 acc[8];
    #pragma unroll
    for (int i = 0; i < 8; ++i) acc[i] = (f32x4){0.f, 0.f, 0.f, 0.f};

    asm volatile("s_waitcnt vmcnt(0)" ::: "memory");
    __syncthreads();

    if (t3 < 2) {
        #pragma unroll
        for (int s = 0; s < 12; ++s) {
            bfx8 fx[2], fw[4];
            #pragma unroll
            for (int i = 0; i < 2; ++i) fx[i] = *(const bfx8*)(xg[i] + s * 512);
            #pragma unroll
            for (int j = 0; j < 4; ++j) fw[j] = *(const bfx8*)(wl + j * 6144 + s * 512);
            #pragma unroll
            for (int i = 0; i < 2; ++i)
                #pragma unroll
                for (int j = 0; j < 4; ++j)
                    acc[i * 4 + j] = __builtin_amdgcn_mfma_f32_16x16x32_bf16(
                        fx[i], fw[j], acc[i * 4 + j], 0, 0, 0);
        }
        // 48^-0.5 * log2(e) folded into Q (softmax uses exp2)
        const float qscale = 0.2082350964f;
        #pragma unroll
        for (int j = 0; j < 4; ++j) {
            int o  = o0 + j * 16 + l15;
            float bi = bias[o];
            int r  = o - t3 * Ck;
            int hd = r / Dk, d = r - hd * Dk;
            bf16* hb = (t3 == 0 ? Qs : Ks) + (size_t)(b * NHk + hd) * 65536
                     + (d >> 3) * 128 + (d & 7);
            #pragma unroll
            for (int i = 0; i < 2; ++i) {
                #pragma unroll
                for (int reg = 0; reg < 4; ++reg) {
                    int npos = n0 + wave * 32 + i * 16 + quad * 4 + reg;
                    float v = acc[i * 4 + j][reg] + bi;
                    if (t3 == 0) v *= qscale;
                    hb[(size_t)(npos >> 4) * 1024 + (npos & 15) * 8] = __float2bfloat16(v);
                }
            }
        }
    } else {
        #pragma unroll
        for (int s = 0; s < 12; ++s) {
            bfx8 fx[2], fw[4];
            #pragma unroll
            for (int i = 0; i < 2; ++i) fx[i] = *(const bfx8*)(xg[i] + s * 512);
            #pragma unroll
            for (int j = 0; j < 4; ++j) fw[j] = *(const bfx8*)(wl + j * 6144 + s * 512);
            #pragma unroll
            for (int j = 0; j < 4; ++j)
                #pragma unroll
                for (int i = 0; i < 2; ++i)
                    acc[j * 2 + i] = __builtin_amdgcn_mfma_f32_16x16x32_bf16(
                        fw[j], fx[i], acc[j * 2 + i], 0, 0, 0);
        }
        #pragma unroll
        for (int j = 0; j < 4; ++j) {
            #pragma unroll
            for (int reg = 0; reg < 4; ++reg) {
                int o  = o0 + j * 16 + quad * 4 + reg;
                float bi = bias[o];
                int r  = o - 2 * Ck;
                int hd = r / Dk, d = r - hd * Dk;
                bf16* vb = Vs + (size_t)(b * NHk + hd) * 49152
                         + ((size_t)(d >> 4) * 128) * 128 + (d & 15) * 8;
                #pragma unroll
                for (int i = 0; i < 2; ++i) {
                    int npos = n0 + wave * 32 + i * 16 + l15;
                    vb[(size_t)(npos >> 3) * 128 + (npos & 7)] =
                        __float2bfloat16(acc[j * 2 + i][reg] + bi);
                }
            }
        }
    }
}

// ---------------------------------------------------------------------------
// Kernel 2 (R11): MFMA attention, LDS-staged K/V. 128 q per block, 32 q per
// wave. Grid (hd, b, bx=8): id%8==hd pins each head's blocks to one XCD.
// Per 64-key chunk: K (8 KB) + V (6 KB) staged once per block via
// global_load_lds (14 x 1KB wave-bursts spread over 4 waves), double
// buffered; one __syncthreads per chunk. All MFMA operands now come from
// LDS (~12 cyc) instead of L2 (~200 cyc); L2 read traffic 459 -> ~124 MB.
// ---------------------------------------------------------------------------
__global__ __launch_bounds__(256, 2) void attn_kernel(
    const bf16* __restrict__ Qs, const bf16* __restrict__ Ks,
    const bf16* __restrict__ Vs, bf16* __restrict__ AO)
{
    __shared__ __align__(16) bf16 KbL[2][4096];   // 8 KB per buf
    __shared__ __align__(16) bf16 VbL[2][3072];   // 6 KB per buf
    __shared__ __align__(16) short Ps[4 * 2 * 1152];
    __shared__ float sums[4][2][16];

    const int hd   = blockIdx.x;
    const int b    = blockIdx.y;
    const int bx   = blockIdx.z;       // 8 q-slabs of 128
    const int t    = threadIdx.x;
    const int wave = t >> 6;
    const int lane = t & 63;
    const int l15  = lane & 15;
    const int quad = lane >> 4;
    const int grp16 = (bx * 4 + wave) * 2;   // first 16-q group of this wave

    const bf16* qb = Qs + (size_t)(b * NHk + hd) * 65536;
    const bf16* kb = Ks + (size_t)(b * NHk + hd) * 65536;
    const bf16* vb = Vs + (size_t)(b * NHk + hd) * 49152;

    // 14 x 1KB pieces per chunk: K halves 0..7 (4 x 2KB), V halves 8..13
    // (3 x 2KB at dc stride 16384 elems). Wave w issues pieces w, w+4, w+8,
    // w+12 — LDS dest wave-uniform, global src per-lane (linear both sides).
    auto stage = [&](int buf, int k0) {
        const bf16* ksrc = kb + (size_t)k0 * 64;
        const bf16* vsrc = vb + (size_t)(k0 >> 3) * 128;
        char* kdst = (char*)&KbL[buf][0];
        char* vdst = (char*)&VbL[buf][0];
        #pragma unroll
        for (int i = 0; i < 4; ++i) {
            const int l = wave + i * 4;
            if (l < 14) {
                const int piece = l >> 1, half = l & 1;
                const bf16* src; char* dst;
                if (piece < 4) {
                    src = ksrc + piece * 1024 + half * 512 + lane * 8;
                    dst = kdst + piece * 2048 + half * 1024;
                } else {
                    const int dc = piece - 4;
                    src = vsrc + (size_t)dc * 16384 + half * 512 + lane * 8;
                    dst = vdst + dc * 2048 + half * 1024;
                }
                gload_lds16(src, dst);
            }
        }
    };

    stage(0, 0);

    // Q fragments (burst loads): B[k=d][n=q=l15] for 2 q-tiles
    bfx8 bq[2][2];
    #pragma unroll
    for (int qt = 0; qt < 2; ++qt) {
        const bf16* qp = qb + ((size_t)(grp16 + qt) * 8 + quad) * 128 + l15 * 8;
        bq[qt][0] = *(const bfx8*)(qp);
        bq[qt][1] = *(const bfx8*)(qp + 512);
    }

    float l_run[2] = {0.f, 0.f};
    f32x4 oacc[2][3];
    #pragma unroll
    for (int qt = 0; qt < 2; ++qt)
        #pragma unroll
        for (int dc = 0; dc < 3; ++dc) oacc[qt][dc] = (f32x4){0.f, 0.f, 0.f, 0.f};

    short* const PsW[2] = { Ps + wave * 2304, Ps + wave * 2304 + 1152 };
    const int lo = quad * 128 + l15 * 8;     // elem offset inside a 2KB piece

    asm volatile("s_waitcnt vmcnt(0)" ::: "memory");
    __syncthreads();

    auto step = [&](int buf, int k0, bool pf) {
        if (pf) stage(buf ^ 1, k0 + 64);     // hides under this chunk's compute

        const bf16* Kc = &KbL[buf][0];
        const bf16* Vc = &VbL[buf][0];

        // S^T = K Q^T: D[key][q], K fragments shared by both q-tiles
        f32x4 sf[2][4];
        #pragma unroll
        for (int s = 0; s < 4; ++s) {
            const bfx8 kf0 = *(const bfx8*)(Kc + s * 1024 + lo);
            const bfx8 kf1 = *(const bfx8*)(Kc + s * 1024 + 512 + lo);
            #pragma unroll
            for (int qt = 0; qt < 2; ++qt) {
                f32x4 z = (f32x4){0.f, 0.f, 0.f, 0.f};
                z = __builtin_amdgcn_mfma_f32_16x16x32_bf16(kf0, bq[qt][0], z, 0, 0, 0);
                z = __builtin_amdgcn_mfma_f32_16x16x32_bf16(kf1, bq[qt][1], z, 0, 0, 0);
                sf[qt][s] = z;
            }
        }

        // exp2 (no max subtraction), pack 4 keys -> b64 write, accumulate l
        #pragma unroll
        for (int qt = 0; qt < 2; ++qt) {
            float lsum = 0.f;
            #pragma unroll
            for (int s = 0; s < 4; ++s) {
                ushort4 pk;
                float e0 = __builtin_amdgcn_exp2f(sf[qt][s][0]);
                float e1 = __builtin_amdgcn_exp2f(sf[qt][s][1]);
                float e2 = __builtin_amdgcn_exp2f(sf[qt][s][2]);
                float e3 = __builtin_amdgcn_exp2f(sf[qt][s][3]);
                lsum += (e0 + e1) + (e2 + e3);
                bf16 h0 = __float2bfloat16(e0), h1 = __float2bfloat16(e1);
                bf16 h2 = __float2bfloat16(e2), h3 = __float2bfloat16(e3);
                pk.x = *(unsigned short*)&h0; pk.y = *(unsigned short*)&h1;
                pk.z = *(unsigned short*)&h2; pk.w = *(unsigned short*)&h3;
                *(ushort4*)&PsW[qt][l15 * 72 + s * 16 + quad * 4] = pk;
            }
            l_run[qt] += lsum;
        }

        // O += P V: A-frags from per-wave LDS, V fragments from staged LDS
        #pragma unroll
        for (int qt = 0; qt < 2; ++qt) {
            const bfx8 ap0 = *(const bfx8*)&PsW[qt][l15 * 72 + quad * 8];
            const bfx8 ap1 = *(const bfx8*)&PsW[qt][l15 * 72 + 32 + quad * 8];
            #pragma unroll
            for (int dc = 0; dc < 3; ++dc) {
                const bfx8 bv0 = *(const bfx8*)(Vc + dc * 1024 + lo);
                const bfx8 bv1 = *(const bfx8*)(Vc + dc * 1024 + 512 + lo);
                oacc[qt][dc] = __builtin_amdgcn_mfma_f32_16x16x32_bf16(
                    ap0, bv0, oacc[qt][dc], 0, 0, 0);
                oacc[qt][dc] = __builtin_amdgcn_mfma_f32_16x16x32_bf16(
                    ap1, bv1, oacc[qt][dc], 0, 0, 0);
            }
        }

        asm volatile("s_waitcnt vmcnt(0)" ::: "memory");  // staged loads landed
        __syncthreads();                                  // buf^1 ready, buf free
    };

    #pragma unroll 1
    for (int k0 = 0; k0 < Nk; k0 += 128) {
        step(0, k0, true);
        step(1, k0 + 64, k0 + 128 < Nk);
    }

    // cross-lane reduce l over quads (per q-tile)
    #pragma unroll
    for (int qt = 0; qt < 2; ++qt) {
        float lt = l_run[qt];
        lt += __shfl_xor(lt, 16, 64);
        lt += __shfl_xor(lt, 32, 64);
        sums[wave][qt][l15] = lt;
    }

    // normalize into per-wave LDS (stride 64 shorts, 16B-aligned rows)
    #pragma unroll
    for (int qt = 0; qt < 2; ++qt) {
        short* OsW = PsW[qt];   // 16*64 = 1024 shorts < 1152 region
        #pragma unroll
        for (int r = 0; r < 4; ++r) {
            int qi = quad * 4 + r;
            float rli = 1.0f / sums[wave][qt][qi];
            #pragma unroll
            for (int dcc = 0; dcc < 3; ++dcc) {
                bf16 hb = __float2bfloat16(oacc[qt][dcc][r] * rli);
                OsW[qi * 64 + dcc * 16 + l15] = *(short*)&hb;
            }
        }
    }

    // swizzled AO store: groups grp16+qt, chunks hd*6 + (0..5); 96 int4 each
    #pragma unroll
    for (int qt = 0; qt < 2; ++qt) {
        bf16* aob = AO + (((size_t)b * 64 + grp16 + qt) * 48 + hd * 6) * 128;
        short* OsW = PsW[qt];
        int u = lane;
        int4 v = *(const int4*)&OsW[(u & 15) * 64 + (u >> 4) * 8];
        *(int4*)(aob + u * 8) = v;
        if (lane < 32) {
            int u2 = 64 + lane;
            int4 v2 = *(const int4*)&OsW[(u2 & 15) * 64 + (u2 >> 4) * 8];
            *(int4*)(aob + u2 * 8) = v2;
        }
    }
}

// ---------------------------------------------------------------------------
// Kernel 3: projection GEMM; W-tile staged in LDS (same as qkv).
// ---------------------------------------------------------------------------
__global__ __launch_bounds__(256) void proj_mfma_kernel(
    const bf16* __restrict__ AO, const bf16* __restrict__ Wp,
    const float* __restrict__ bias, float* __restrict__ out)
{
    __shared__ __align__(16) bf16 Wl[24576];    // 48 KB

    const int b    = blockIdx.z;
    const int by   = blockIdx.y;
    const int bx   = blockIdx.x;
    const int o0   = by * 64;
    const int n0   = bx * 128;
    const int wave = threadIdx.x >> 6;
    const int lane = threadIdx.x & 63;
    const int l15  = lane & 15, quad = lane >> 4;

    {
        const bf16* wsrc = Wp + (size_t)by * 24576;
        #pragma unroll
        for (int i = 0; i < 12; ++i) {
            int f = wave * 12 + i;
            gload_lds16(wsrc + f * 512 + lane * 8, (char*)Wl + f * 1024);
        }
    }

    const bf16* ag[2];
    #pragma unroll
    for (int i = 0; i < 2; ++i)
        ag[i] = AO + ((size_t)(b * 64 + bx * 8 + wave * 2 + i) * 48) * 128 + lane * 8;
    const bf16* wl = Wl + lane * 8;

    f32x4 acc[8];
    #pragma unroll
    for (int i = 0; i < 8; ++i) acc[i] = (f32x4){0.f, 0.f, 0.f, 0.f};

    asm volatile("s_waitcnt vmcnt(0)" ::: "memory");
    __syncthreads();

    #pragma unroll
    for (int s = 0; s < 12; ++s) {
        bfx8 fx[2], fw[4];
        #pragma unroll
        for (int i = 0; i < 2; ++i) fx[i] = *(const bfx8*)(ag[i] + s * 512);
        #pragma unroll
        for (int j = 0; j < 4; ++j) fw[j] = *(const bfx8*)(wl + j * 6144 + s * 512);
        #pragma unroll
        for (int j = 0; j < 4; ++j)
            #pragma unroll
            for (int i = 0; i < 2; ++i)
                acc[j * 2 + i] = __builtin_amdgcn_mfma_f32_16x16x32_bf16(
                    fw[j], fx[i], acc[j * 2 + i], 0, 0, 0);
    }

    #pragma unroll
    for (int j = 0; j < 4; ++j) {
        #pragma unroll
        for (int reg = 0; reg < 4; ++reg) {
            int o  = o0 + j * 16 + quad * 4 + reg;
            float bi = bias[o];
            #pragma unroll
            for (int i = 0; i < 2; ++i) {
                int npos = n0 + wave * 32 + i * 16 + l15;
                out[((size_t)b * Ck + o) * Nk + npos] = acc[j * 2 + i][reg] + bi;
            }
        }
    }
}

extern "C" void kernel_launch(void* const* d_in, const int* in_sizes, int n_in,
                              void* d_out, int out_size, void* d_ws, size_t ws_size,
                              hipStream_t stream)
{
    const float* x      = (const float*)d_in[0];
    const float* w_qkv  = (const float*)d_in[1];
    const float* b_qkv  = (const float*)d_in[2];
    const float* w_proj = (const float*)d_in[3];
    const float* b_proj = (const float*)d_in[4];
    float* out = (float*)d_out;

    const size_t XT_SEG = (size_t)Bk * Nk * Ck;
    const size_t WQ_SEG = (size_t)O3 * Ck;
    const size_t WP_SEG = (size_t)Ck * Ck;
    const size_t QK_SEG = (size_t)Bk * NHk * Nk * Dp;
    const size_t V_SEG  = (size_t)Bk * NHk * Dk * Nk;

    bf16* Xs = (bf16*)d_ws;
    bf16* Wq = Xs + XT_SEG;
    bf16* Wp = Wq + WQ_SEG;
    bf16* Qs = Wp + WP_SEG;
    bf16* Ks = Qs + QK_SEG;
    bf16* Vs = Ks + QK_SEG;
    bf16* AO = Vs + V_SEG;

    prep_kernel<<<3072 + (O3 * Ck + 255) / 256, 256, 0, stream>>>(
        x, Xs, w_qkv, w_proj, Wq, Wp, Qs, Ks);
    qkv_mfma_kernel<<<dim3(Nk / 128, O3 / 64, Bk), 256, 0, stream>>>(
        Xs, Wq, b_qkv, Qs, Ks, Vs);
    attn_kernel<<<dim3(NHk, Bk, 8), 256, 0, stream>>>(Qs, Ks, Vs, AO);
    proj_mfma_kernel<<<dim3(Nk / 128, Ck / 64, Bk), 256, 0, stream>>>(
        AO, Wp, b_proj, out);
}

// Round 4
// 120.125 us; speedup vs baseline: 1.1325x; 1.0028x over previous
//
#include <hip/hip_runtime.h>
#include <hip/hip_bf16.h>

typedef __hip_bfloat16 bf16;
typedef __bf16 bfx8 __attribute__((ext_vector_type(8)));
typedef float f32x4 __attribute__((ext_vector_type(4)));

#define Bk   8
#define Ck   384
#define NHk  8
#define Dk   48
#define Dp   64
#define Nk   1024
#define O3   1152

// ---------------------------------------------------------------------------
// R13 = R11 (verified 120.5us, 4 launches) + the safe R12 wins:
//   - vectorized epilogues via MFMA operand swap (acc regs contiguous in
//     output: qkv Q/K 8B ushort4 stores, qkv V 8B, proj 16B float4)
//   - LDS-free vectorized prep (1 unit/thread, int4 stores), single launch
// R12's single-cooperative-kernel fusion REVERTED: nondeterministic absmax
// (0.4..468) = stale-data race across grid.sync phases (per-XCD L2 non-
// coherence / graph-capture interaction). Multi-kernel boundaries give the
// needed release/acquire for free.
//
// Workspace (bf16 elems):
//   Xs: [b][n/16][48][16][8]   Wq/Wp: [o/16][48][16][8]
//   Qs/Ks: [b][hd][n/16][8][16][8]  (chunks 6,7 zero; qscale folded in Q)
//   Vs: [b][hd][d/16][n/8][16][8]   AO: [b][n/16][48][16][8]
// ---------------------------------------------------------------------------

__device__ __forceinline__ void gload_lds16(const bf16* src, void* dst)
{
    __builtin_amdgcn_global_load_lds(
        (const __attribute__((address_space(1))) void*)src,
        (__attribute__((address_space(3))) void*)dst, 16, 0, 0);
}

__device__ __forceinline__ int pack2(float a, float b)
{
    bf16 ha = __float2bfloat16(a), hb = __float2bfloat16(b);
    unsigned lo = *(unsigned short*)&ha, hi = *(unsigned short*)&hb;
    return (int)(lo | (hi << 16));
}

__device__ __forceinline__ ushort4 pack4(float v0, float v1, float v2, float v3)
{
    bf16 h0 = __float2bfloat16(v0), h1 = __float2bfloat16(v1);
    bf16 h2 = __float2bfloat16(v2), h3 = __float2bfloat16(v3);
    ushort4 pk;
    pk.x = *(unsigned short*)&h0; pk.y = *(unsigned short*)&h1;
    pk.z = *(unsigned short*)&h2; pk.w = *(unsigned short*)&h3;
    return pk;
}

// ---------------------------------------------------------------------------
// Prep: one unit per thread, 729088 units = 2848 blocks x 256.
//   [0,393216)        xpose: 8 channels -> one int4 fragment store
//   [393216,448512)   wqkv convert (8c -> int4)
//   [448512,466944)   wproj convert
//   [466944,729088)   zero Q/K pad chunks (cd=6,7)
// ---------------------------------------------------------------------------
__global__ __launch_bounds__(256) void prep_kernel(
    const float* __restrict__ x, bf16* __restrict__ Xs,
    const float* __restrict__ wq, const float* __restrict__ wp,
    bf16* __restrict__ Wq, bf16* __restrict__ Wp,
    bf16* __restrict__ Qs, bf16* __restrict__ Ks)
{
    const int u = blockIdx.x * 256 + threadIdx.x;
    if (u < 393216) {
        int n = u & 1023, rest = u >> 10;
        int oct = rest % 48, b = rest / 48;
        const float* xb = x + (size_t)b * Ck * Nk;
        float f[8];
        #pragma unroll
        for (int e = 0; e < 8; ++e) f[e] = xb[(size_t)(oct * 8 + e) * Nk + n];
        int4 v = { pack2(f[0], f[1]), pack2(f[2], f[3]),
                   pack2(f[4], f[5]), pack2(f[6], f[7]) };
        bf16* dst = Xs + ((size_t)b * 64 + (n >> 4)) * 6144 + oct * 128 + (n & 15) * 8;
        *(int4*)dst = v;
    } else if (u < 448512) {
        int u1 = u - 393216;
        int o = u1 % 1152, oct = u1 / 1152;
        const float* src = wq + (size_t)o * Ck + oct * 8;
        int4 v = { pack2(src[0], src[1]), pack2(src[2], src[3]),
                   pack2(src[4], src[5]), pack2(src[6], src[7]) };
        bf16* dst = Wq + ((size_t)(o >> 4) * 48 + oct) * 128 + (o & 15) * 8;
        *(int4*)dst = v;
    } else if (u < 466944) {
        int u2 = u - 448512;
        int o = u2 % 384, oct = u2 / 384;
        const float* src = wp + (size_t)o * Ck + oct * 8;
        int4 v = { pack2(src[0], src[1]), pack2(src[2], src[3]),
                   pack2(src[4], src[5]), pack2(src[6], src[7]) };
        bf16* dst = Wp + ((size_t)(o >> 4) * 48 + oct) * 128 + (o & 15) * 8;
        *(int4*)dst = v;
    } else {
        int i = u - 466944;      // 2 bufs x 64 heads x 64 grp x 2 chunks x 16
        int buf = i >> 17;
        int r17 = i & 131071;
        int head = r17 >> 11;
        int r11 = r17 & 2047;
        int g = r11 >> 5, c5 = r11 & 31;
        int cd = 6 + (c5 >> 4), e = c5 & 15;
        bf16* p = (buf ? Ks : Qs) + (size_t)head * 65536 +
                  ((size_t)g * 8 + cd) * 128 + e * 8;
        *(int4*)p = (int4){0, 0, 0, 0};
    }
}

// ---------------------------------------------------------------------------
// Kernel 1: QKV GEMM, W-tile in LDS, vectorized epilogues.
// ---------------------------------------------------------------------------
__global__ __launch_bounds__(256) void qkv_mfma_kernel(
    const bf16* __restrict__ Xs, const bf16* __restrict__ Wq,
    const float* __restrict__ bias,
    bf16* __restrict__ Qs, bf16* __restrict__ Ks, bf16* __restrict__ Vs)
{
    __shared__ __align__(16) bf16 Wl[24576];    // 48 KB

    const int b    = blockIdx.z;
    const int by   = blockIdx.y;
    const int bx   = blockIdx.x;
    const int o0   = by * 64;
    const int n0   = bx * 128;
    const int wave = threadIdx.x >> 6;
    const int lane = threadIdx.x & 63;
    const int l15  = lane & 15, quad = lane >> 4;
    const int t3   = o0 / Ck;

    // stage W tile: 48 x 1KB fragment bursts, 12 per wave
    {
        const bf16* wsrc = Wq + (size_t)by * 24576;
        #pragma unroll
        for (int i = 0; i < 12; ++i) {
            int f = wave * 12 + i;
            gload_lds16(wsrc + f * 512 + lane * 8, (char*)Wl + f * 1024);
        }
    }

    const bf16* xg[2];
    #pragma unroll
    for (int i = 0; i < 2; ++i)
        xg[i] = Xs + ((size_t)(b * 64 + bx * 8 + wave * 2 + i) * 48) * 128 + lane * 8;
    const bf16* wl = Wl + lane * 8;

    f32x4 acc[8];
    #pragma unroll
    for (int i = 0; i < 8; ++i) acc[i] = (f32x4){0.f, 0.f, 0.f, 0.f};

    asm volatile("s_waitcnt vmcnt(0)" ::: "memory");
    __syncthreads();

    if (t3 < 2) {
        // D: row = o (quad*4+reg), col = n (l15) -> 4 consecutive d -> 8B store
        #pragma unroll
        for (int s = 0; s < 12; ++s) {
            bfx8 fx[2], fw[4];
            #pragma unroll
            for (int i = 0; i < 2; ++i) fx[i] = *(const bfx8*)(xg[i] + s * 512);
            #pragma unroll
            for (int j = 0; j < 4; ++j) fw[j] = *(const bfx8*)(wl + j * 6144 + s * 512);
            #pragma unroll
            for (int j = 0; j < 4; ++j)
                #pragma unroll
                for (int i = 0; i < 2; ++i)
                    acc[j * 2 + i] = __builtin_amdgcn_mfma_f32_16x16x32_bf16(
                        fw[j], fx[i], acc[j * 2 + i], 0, 0, 0);
        }
        const float qscale = 0.2082350964f;   // 48^-0.5 * log2(e)
        #pragma unroll
        for (int j = 0; j < 4; ++j) {
            int ob = o0 + j * 16 + quad * 4;          // o of reg 0 (mult of 4)
            float4 bi = *(const float4*)&bias[ob];
            int r  = ob - t3 * Ck;
            int hd = r / Dk, d0 = r - hd * Dk;        // d0..d0+3, same octet
            bf16* hb = (t3 == 0 ? Qs : Ks) + (size_t)(b * NHk + hd) * 65536
                     + (d0 >> 3) * 128 + (d0 & 7);
            #pragma unroll
            for (int i = 0; i < 2; ++i) {
                int npos = n0 + wave * 32 + i * 16 + l15;
                f32x4 a = acc[j * 2 + i];
                float v0 = a[0] + bi.x, v1 = a[1] + bi.y;
                float v2 = a[2] + bi.z, v3 = a[3] + bi.w;
                if (t3 == 0) { v0 *= qscale; v1 *= qscale; v2 *= qscale; v3 *= qscale; }
                *(ushort4*)(hb + (size_t)(npos >> 4) * 1024 + (npos & 15) * 8) =
                    pack4(v0, v1, v2, v3);
            }
        }
    } else {
        // D: row = n (quad*4+reg), col = o (l15) -> 4 consecutive n -> 8B store
        #pragma unroll
        for (int s = 0; s < 12; ++s) {
            bfx8 fx[2], fw[4];
            #pragma unroll
            for (int i = 0; i < 2; ++i) fx[i] = *(const bfx8*)(xg[i] + s * 512);
            #pragma unroll
            for (int j = 0; j < 4; ++j) fw[j] = *(const bfx8*)(wl + j * 6144 + s * 512);
            #pragma unroll
            for (int i = 0; i < 2; ++i)
                #pragma unroll
                for (int j = 0; j < 4; ++j)
                    acc[i * 4 + j] = __builtin_amdgcn_mfma_f32_16x16x32_bf16(
                        fx[i], fw[j], acc[i * 4 + j], 0, 0, 0);
        }
        #pragma unroll
        for (int j = 0; j < 4; ++j) {
            int ov = o0 + j * 16 + l15;
            float bi = bias[ov];
            int r  = ov - 2 * Ck;
            int hd = r / Dk, d = r - hd * Dk;
            bf16* vbp = Vs + (size_t)(b * NHk + hd) * 49152
                      + (size_t)(d >> 4) * 16384 + (d & 15) * 8;
            #pragma unroll
            for (int i = 0; i < 2; ++i) {
                int npb = n0 + wave * 32 + i * 16 + quad * 4;   // n of reg 0
                f32x4 a = acc[i * 4 + j];
                *(ushort4*)(vbp + (size_t)(npb >> 3) * 128 + (npb & 7)) =
                    pack4(a[0] + bi, a[1] + bi, a[2] + bi, a[3] + bi);
            }
        }
    }
}

// ---------------------------------------------------------------------------
// Kernel 2: MFMA attention, LDS-staged K/V (verbatim R11, passed).
// ---------------------------------------------------------------------------
__global__ __launch_bounds__(256, 2) void attn_kernel(
    const bf16* __restrict__ Qs, const bf16* __restrict__ Ks,
    const bf16* __restrict__ Vs, bf16* __restrict__ AO)
{
    __shared__ __align__(16) bf16 KbL[2][4096];   // 8 KB per buf
    __shared__ __align__(16) bf16 VbL[2][3072];   // 6 KB per buf
    __shared__ __align__(16) short Ps[4 * 2 * 1152];
    __shared__ float sums[4][2][16];

    const int hd   = blockIdx.x;
    const int b    = blockIdx.y;
    const int bx   = blockIdx.z;       // 8 q-slabs of 128
    const int t    = threadIdx.x;
    const int wave = t >> 6;
    const int lane = t & 63;
    const int l15  = lane & 15;
    const int quad = lane >> 4;
    const int grp16 = (bx * 4 + wave) * 2;   // first 16-q group of this wave

    const bf16* qb = Qs + (size_t)(b * NHk + hd) * 65536;
    const bf16* kb = Ks + (size_t)(b * NHk + hd) * 65536;
    const bf16* vb = Vs + (size_t)(b * NHk + hd) * 49152;

    auto stage = [&](int buf, int k0) {
        const bf16* ksrc = kb + (size_t)k0 * 64;
        const bf16* vsrc = vb + (size_t)(k0 >> 3) * 128;
        char* kdst = (char*)&KbL[buf][0];
        char* vdst = (char*)&VbL[buf][0];
        #pragma unroll
        for (int i = 0; i < 4; ++i) {
            const int l = wave + i * 4;
            if (l < 14) {
                const int piece = l >> 1, half = l & 1;
                const bf16* src; char* dst;
                if (piece < 4) {
                    src = ksrc + piece * 1024 + half * 512 + lane * 8;
                    dst = kdst + piece * 2048 + half * 1024;
                } else {
                    const int dc = piece - 4;
                    src = vsrc + (size_t)dc * 16384 + half * 512 + lane * 8;
                    dst = vdst + dc * 2048 + half * 1024;
                }
                gload_lds16(src, dst);
            }
        }
    };

    stage(0, 0);

    bfx8 bq[2][2];
    #pragma unroll
    for (int qt = 0; qt < 2; ++qt) {
        const bf16* qp = qb + ((size_t)(grp16 + qt) * 8 + quad) * 128 + l15 * 8;
        bq[qt][0] = *(const bfx8*)(qp);
        bq[qt][1] = *(const bfx8*)(qp + 512);
    }

    float l_run[2] = {0.f, 0.f};
    f32x4 oacc[2][3];
    #pragma unroll
    for (int qt = 0; qt < 2; ++qt)
        #pragma unroll
        for (int dc = 0; dc < 3; ++dc) oacc[qt][dc] = (f32x4){0.f, 0.f, 0.f, 0.f};

    short* const PsW[2] = { Ps + wave * 2304, Ps + wave * 2304 + 1152 };
    const int lo = quad * 128 + l15 * 8;     // elem offset inside a 2KB piece

    asm volatile("s_waitcnt vmcnt(0)" ::: "memory");
    __syncthreads();

    auto step = [&](int buf, int k0, bool pf) {
        if (pf) stage(buf ^ 1, k0 + 64);     // hides under this chunk's compute

        const bf16* Kc = &KbL[buf][0];
        const bf16* Vc = &VbL[buf][0];

        f32x4 sf[2][4];
        #pragma unroll
        for (int s = 0; s < 4; ++s) {
            const bfx8 kf0 = *(const bfx8*)(Kc + s * 1024 + lo);
            const bfx8 kf1 = *(const bfx8*)(Kc + s * 1024 + 512 + lo);
            #pragma unroll
            for (int qt = 0; qt < 2; ++qt) {
                f32x4 z = (f32x4){0.f, 0.f, 0.f, 0.f};
                z = __builtin_amdgcn_mfma_f32_16x16x32_bf16(kf0, bq[qt][0], z, 0, 0, 0);
                z = __builtin_amdgcn_mfma_f32_16x16x32_bf16(kf1, bq[qt][1], z, 0, 0, 0);
                sf[qt][s] = z;
            }
        }

        #pragma unroll
        for (int qt = 0; qt < 2; ++qt) {
            float lsum = 0.f;
            #pragma unroll
            for (int s = 0; s < 4; ++s) {
                float e0 = __builtin_amdgcn_exp2f(sf[qt][s][0]);
                float e1 = __builtin_amdgcn_exp2f(sf[qt][s][1]);
                float e2 = __builtin_amdgcn_exp2f(sf[qt][s][2]);
                float e3 = __builtin_amdgcn_exp2f(sf[qt][s][3]);
                lsum += (e0 + e1) + (e2 + e3);
                *(ushort4*)&PsW[qt][l15 * 72 + s * 16 + quad * 4] =
                    pack4(e0, e1, e2, e3);
            }
            l_run[qt] += lsum;
        }

        #pragma unroll
        for (int qt = 0; qt < 2; ++qt) {
            const bfx8 ap0 = *(const bfx8*)&PsW[qt][l15 * 72 + quad * 8];
            const bfx8 ap1 = *(const bfx8*)&PsW[qt][l15 * 72 + 32 + quad * 8];
            #pragma unroll
            for (int dc = 0; dc < 3; ++dc) {
                const bfx8 bv0 = *(const bfx8*)(Vc + dc * 1024 + lo);
                const bfx8 bv1 = *(const bfx8*)(Vc + dc * 1024 + 512 + lo);
                oacc[qt][dc] = __builtin_amdgcn_mfma_f32_16x16x32_bf16(
                    ap0, bv0, oacc[qt][dc], 0, 0, 0);
                oacc[qt][dc] = __builtin_amdgcn_mfma_f32_16x16x32_bf16(
                    ap1, bv1, oacc[qt][dc], 0, 0, 0);
            }
        }

        asm volatile("s_waitcnt vmcnt(0)" ::: "memory");  // staged loads landed
        __syncthreads();                                  // buf^1 ready, buf free
    };

    #pragma unroll 1
    for (int k0 = 0; k0 < Nk; k0 += 128) {
        step(0, k0, true);
        step(1, k0 + 64, k0 + 128 < Nk);
    }

    #pragma unroll
    for (int qt = 0; qt < 2; ++qt) {
        float lt = l_run[qt];
        lt += __shfl_xor(lt, 16, 64);
        lt += __shfl_xor(lt, 32, 64);
        sums[wave][qt][l15] = lt;
    }
    asm volatile("s_waitcnt lgkmcnt(0)" ::: "memory");

    #pragma unroll
    for (int qt = 0; qt < 2; ++qt) {
        short* OsW = PsW[qt];   // 16*64 = 1024 shorts < 1152 region
        #pragma unroll
        for (int r = 0; r < 4; ++r) {
            int qi = quad * 4 + r;
            float rli = 1.0f / sums[wave][qt][qi];
            #pragma unroll
            for (int dcc = 0; dcc < 3; ++dcc) {
                bf16 hb = __float2bfloat16(oacc[qt][dcc][r] * rli);
                OsW[qi * 64 + dcc * 16 + l15] = *(short*)&hb;
            }
        }
    }
    asm volatile("s_waitcnt lgkmcnt(0)" ::: "memory");

    #pragma unroll
    for (int qt = 0; qt < 2; ++qt) {
        bf16* aob = AO + (((size_t)b * 64 + grp16 + qt) * 48 + hd * 6) * 128;
        short* OsW = PsW[qt];
        int u = lane;
        int4 v = *(const int4*)&OsW[(u & 15) * 64 + (u >> 4) * 8];
        *(int4*)(aob + u * 8) = v;
        if (lane < 32) {
            int u2 = 64 + lane;
            int4 v2 = *(const int4*)&OsW[(u2 & 15) * 64 + (u2 >> 4) * 8];
            *(int4*)(aob + u2 * 8) = v2;
        }
    }
}

// ---------------------------------------------------------------------------
// Kernel 3: projection GEMM; W in LDS, vectorized float4 epilogue.
// ---------------------------------------------------------------------------
__global__ __launch_bounds__(256) void proj_mfma_kernel(
    const bf16* __restrict__ AO, const bf16* __restrict__ Wp,
    const float* __restrict__ bias, float* __restrict__ out)
{
    __shared__ __align__(16) bf16 Wl[24576];    // 48 KB

    const int b    = blockIdx.z;
    const int by   = blockIdx.y;
    const int bx   = blockIdx.x;
    const int o0   = by * 64;
    const int n0   = bx * 128;
    const int wave = threadIdx.x >> 6;
    const int lane = threadIdx.x & 63;
    const int l15  = lane & 15, quad = lane >> 4;

    {
        const bf16* wsrc = Wp + (size_t)by * 24576;
        #pragma unroll
        for (int i = 0; i < 12; ++i) {
            int f = wave * 12 + i;
            gload_lds16(wsrc + f * 512 + lane * 8, (char*)Wl + f * 1024);
        }
    }

    const bf16* ag[2];
    #pragma unroll
    for (int i = 0; i < 2; ++i)
        ag[i] = AO + ((size_t)(b * 64 + bx * 8 + wave * 2 + i) * 48) * 128 + lane * 8;
    const bf16* wl = Wl + lane * 8;

    f32x4 acc[8];
    #pragma unroll
    for (int i = 0; i < 8; ++i) acc[i] = (f32x4){0.f, 0.f, 0.f, 0.f};

    asm volatile("s_waitcnt vmcnt(0)" ::: "memory");
    __syncthreads();

    // D: row = n (quad*4+reg), col = o (l15) -> float4 stores
    #pragma unroll
    for (int s = 0; s < 12; ++s) {
        bfx8 fx[2], fw[4];
        #pragma unroll
        for (int i = 0; i < 2; ++i) fx[i] = *(const bfx8*)(ag[i] + s * 512);
        #pragma unroll
        for (int j = 0; j < 4; ++j) fw[j] = *(const bfx8*)(wl + j * 6144 + s * 512);
        #pragma unroll
        for (int i = 0; i < 2; ++i)
            #pragma unroll
            for (int j = 0; j < 4; ++j)
                acc[i * 4 + j] = __builtin_amdgcn_mfma_f32_16x16x32_bf16(
                    fx[i], fw[j], acc[i * 4 + j], 0, 0, 0);
    }

    #pragma unroll
    for (int j = 0; j < 4; ++j) {
        int o = o0 + j * 16 + l15;
        float bi = bias[o];
        #pragma unroll
        for (int i = 0; i < 2; ++i) {
            int npb = n0 + wave * 32 + i * 16 + quad * 4;
            f32x4 a = acc[i * 4 + j];
            float4 v = { a[0] + bi, a[1] + bi, a[2] + bi, a[3] + bi };
            *(float4*)&out[((size_t)b * Ck + o) * Nk + npb] = v;
        }
    }
}

extern "C" void kernel_launch(void* const* d_in, const int* in_sizes, int n_in,
                              void* d_out, int out_size, void* d_ws, size_t ws_size,
                              hipStream_t stream)
{
    const float* x      = (const float*)d_in[0];
    const float* w_qkv  = (const float*)d_in[1];
    const float* b_qkv  = (const float*)d_in[2];
    const float* w_proj = (const float*)d_in[3];
    const float* b_proj = (const float*)d_in[4];
    float* out = (float*)d_out;

    const size_t XT_SEG = (size_t)Bk * Nk * Ck;
    const size_t WQ_SEG = (size_t)O3 * Ck;
    const size_t WP_SEG = (size_t)Ck * Ck;
    const size_t QK_SEG = (size_t)Bk * NHk * Nk * Dp;
    const size_t V_SEG  = (size_t)Bk * NHk * Dk * Nk;

    bf16* Xs = (bf16*)d_ws;
    bf16* Wq = Xs + XT_SEG;
    bf16* Wp = Wq + WQ_SEG;
    bf16* Qs = Wp + WP_SEG;
    bf16* Ks = Qs + QK_SEG;
    bf16* Vs = Ks + QK_SEG;
    bf16* AO = Vs + V_SEG;

    prep_kernel<<<2848, 256, 0, stream>>>(x, Xs, w_qkv, w_proj, Wq, Wp, Qs, Ks);
    qkv_mfma_kernel<<<dim3(Nk / 128, O3 / 64, Bk), 256, 0, stream>>>(
        Xs, Wq, b_qkv, Qs, Ks, Vs);
    attn_kernel<<<dim3(NHk, Bk, 8), 256, 0, stream>>>(Qs, Ks, Vs, AO);
    proj_mfma_kernel<<<dim3(Nk / 128, Ck / 64, Bk), 256, 0, stream>>>(
        AO, Wp, b_proj, out);
}